// Round 6
// baseline (228.692 us; speedup 1.0000x reference)
//
#include <hip/hip_runtime.h>
#include <hip/hip_bf16.h>
#include <math.h>

#define N_NODES 50000
#define N_EDGES 1600000
#define IN_F 256
#define OUT_F 128
#define ALPHA 0.2f
#define EPS 1e-9f

#define RANGES 8                            // = #XCDs
#define NPR (N_NODES / RANGES)              // 6250 nodes per range
#define CAP 96                              // bucket capacity; P(deg>96)*N ~ 5e-14
#define TILE 2048                           // edges staged per block-iteration
#define BINCAP 205000                       // per-range bin capacity (E[.]=200000, +12 sigma)

// ---------------------------------------------------------------------------
// Kernel 1: h = x @ W (f32 vector GEMM), h stored as bf16.
// Epilogue fused: s1[n] = h[n]·a[0:128], s2[n] = h[n]·a[128:256] (from f32 acc)
// ---------------------------------------------------------------------------
#define G_ROWS 32
#define G_BK 64
#define XPAD (G_ROWS + 4)

__device__ __forceinline__ unsigned pack_bf16(float a, float b) {
  unsigned ua = __float_as_uint(a);
  unsigned ub = __float_as_uint(b);
  ua = (ua + 0x7FFFu + ((ua >> 16) & 1u)) >> 16;   // RNE
  ub = (ub + 0x7FFFu + ((ub >> 16) & 1u)) >> 16;
  return ua | (ub << 16);
}

__global__ __launch_bounds__(256) void gemm_xw(const float* __restrict__ x,
                                               const float* __restrict__ W,
                                               const float* __restrict__ a,
                                               unsigned* __restrict__ hb,  // bf16x2
                                               float* __restrict__ s1,
                                               float* __restrict__ s2) {
  __shared__ float ws[G_BK][OUT_F];
  __shared__ float xs[G_BK][XPAD];
  const int t = threadIdx.x;
  const int row0 = blockIdx.x * G_ROWS;
  const int tc = t & 31;
  const int tr = t >> 5;
  const int c0 = tc * 4;
  const int r0 = tr * 4;
  float acc[4][4] = {};

  for (int k0 = 0; k0 < IN_F; k0 += G_BK) {
    __syncthreads();
    const float4* Wg = reinterpret_cast<const float4*>(W + (size_t)k0 * OUT_F);
    float4* wsf = reinterpret_cast<float4*>(&ws[0][0]);
#pragma unroll
    for (int j = 0; j < 8; ++j)
      wsf[t + j * 256] = Wg[t + j * 256];
#pragma unroll
    for (int j = 0; j < 2; ++j) {
      int f = t + j * 256;
      int r = f >> 4;
      int kk = (f & 15) * 4;
      int gr = row0 + r;
      if (gr >= N_NODES) gr = N_NODES - 1;
      float4 v = *reinterpret_cast<const float4*>(&x[(size_t)gr * IN_F + k0 + kk]);
      xs[kk + 0][r] = v.x; xs[kk + 1][r] = v.y;
      xs[kk + 2][r] = v.z; xs[kk + 3][r] = v.w;
    }
    __syncthreads();
#pragma unroll
    for (int k = 0; k < G_BK; ++k) {
      float4 wv = *reinterpret_cast<const float4*>(&ws[k][c0]);
      float4 xv = *reinterpret_cast<const float4*>(&xs[k][r0]);
      float xa[4] = {xv.x, xv.y, xv.z, xv.w};
      float wa[4] = {wv.x, wv.y, wv.z, wv.w};
#pragma unroll
      for (int i = 0; i < 4; ++i)
#pragma unroll
        for (int j = 0; j < 4; ++j)
          acc[i][j] = fmaf(xa[i], wa[j], acc[i][j]);
    }
  }

  float4 as = *reinterpret_cast<const float4*>(&a[c0]);
  float4 ad = *reinterpret_cast<const float4*>(&a[OUT_F + c0]);
#pragma unroll
  for (int i = 0; i < 4; ++i) {
    int gr = row0 + r0 + i;
    if (gr < N_NODES) {
      uint2 o = {pack_bf16(acc[i][0], acc[i][1]), pack_bf16(acc[i][2], acc[i][3])};
      *reinterpret_cast<uint2*>(&hb[(size_t)gr * 64 + tc * 2]) = o;
    }
    float p1 = acc[i][0] * as.x + acc[i][1] * as.y + acc[i][2] * as.z + acc[i][3] * as.w;
    float p2 = acc[i][0] * ad.x + acc[i][1] * ad.y + acc[i][2] * ad.z + acc[i][3] * ad.w;
#pragma unroll
    for (int m = 16; m >= 1; m >>= 1) {
      p1 += __shfl_xor(p1, m, 64);
      p2 += __shfl_xor(p2, m, 64);
    }
    if (tc == 0 && gr < N_NODES) { s1[gr] = p1; s2[gr] = p2; }
  }
}

// ---------------------------------------------------------------------------
// int32-vs-int64 detection (values < 50000 => odd words all zero)
// ---------------------------------------------------------------------------
__global__ void detect_i64(const int* __restrict__ ei, int* __restrict__ flag) {
  int lane = threadIdx.x & 63;
  int nz = 0;
#pragma unroll
  for (int j = 0; j < 4; ++j)
    nz |= ei[2 * (lane + j * 64) + 1];
  unsigned long long anynz = __ballot(nz != 0);
  if (lane == 0) *flag = (anynz == 0ull) ? 1 : 0;
}

__device__ __forceinline__ int load_idx(const int* __restrict__ ei32, int isI64,
                                        long long pos) {
  if (isI64) return (int)(reinterpret_cast<const long long*>(ei32)[pos]);
  return ei32[pos];
}

// ---------------------------------------------------------------------------
// Kernel 2: radix partition of edges into 8 node-range bins (LDS counting
// sort per 2048-edge tile; one cursor atomic per bin per tile; contiguous
// ~2 KB segment writes -> full-line writebacks).
// ---------------------------------------------------------------------------
__global__ __launch_bounds__(256) void part_k(const int* __restrict__ ei,
                                              const int* __restrict__ i64flag,
                                              uint2* __restrict__ bins,
                                              int* __restrict__ bincur) {
  __shared__ uint2 buf[TILE];            // 16 KB
  __shared__ int hist[RANGES], pre[RANGES + 1], cur[RANGES], gbase[RANGES];
  const int t = threadIdx.x;
  const int f64 = *i64flag;
  const int ntiles = (N_EDGES + TILE - 1) / TILE;
  for (int tile = blockIdx.x; tile < ntiles; tile += gridDim.x) {
    const int base = tile * TILE;
    if (t < RANGES) hist[t] = 0;
    __syncthreads();
    int ss[8], dd[8], bb[8];
#pragma unroll
    for (int j = 0; j < 8; ++j) {
      int e = base + j * 256 + t;
      if (e < N_EDGES) {
        ss[j] = load_idx(ei, f64, e);
        dd[j] = load_idx(ei, f64, (long long)N_EDGES + e);
        bb[j] = (int)((unsigned)ss[j] / (unsigned)NPR);
        atomicAdd(&hist[bb[j]], 1);
      } else {
        bb[j] = -1; ss[j] = 0; dd[j] = 0;
      }
    }
    __syncthreads();
    if (t == 0) {
      int run = 0;
#pragma unroll
      for (int b = 0; b < RANGES; ++b) { pre[b] = run; run += hist[b]; }
      pre[RANGES] = run;
    }
    if (t < RANGES) gbase[t] = atomicAdd(&bincur[t], hist[t]);
    __syncthreads();
    if (t < RANGES) cur[t] = pre[t];
    __syncthreads();
#pragma unroll
    for (int j = 0; j < 8; ++j) {
      if (bb[j] >= 0) {
        int pos = atomicAdd(&cur[bb[j]], 1);
        buf[pos] = make_uint2((unsigned)ss[j], (unsigned)dd[j]);
      }
    }
    __syncthreads();
    const int tot = pre[RANGES];
    for (int i = t; i < tot; i += 256) {
      uint2 v = buf[i];
      int b = (int)(v.x / (unsigned)NPR);
      long long o = (long long)gbase[b] + (i - pre[b]);
      if (o < BINCAP) bins[(size_t)b * BINCAP + o] = v;
    }
    __syncthreads();
  }
}

// ---------------------------------------------------------------------------
// Kernel 3: bucket fill from XCD-local bin. Range r's working set (1.6 MB bin
// stream + 2.4 MB bucket slice + cnt lines) fits in one XCD's 4 MB L2.
// ---------------------------------------------------------------------------
__global__ __launch_bounds__(256) void fill2_k(const uint2* __restrict__ bins,
                                               const int* __restrict__ bincur,
                                               int* __restrict__ cnt,
                                               int* __restrict__ edst) {
  const int r = blockIdx.x & 7;
  const int sub = blockIdx.x >> 3;
  const int nsub = gridDim.x >> 3;
  int n_r = bincur[r];
  if (n_r > BINCAP) n_r = BINCAP;
  const uint2* bp = bins + (size_t)r * BINCAP;
  for (int i = sub * 256 + threadIdx.x; i < n_r; i += nsub * 256) {
    uint2 v = bp[i];
    int p = atomicAdd(&cnt[v.x], 1);
    if (p < CAP) edst[(size_t)v.x * CAP + p] = (int)v.y;
  }
}

// ---------------------------------------------------------------------------
// Kernel 4: gather-aggregate. One wave per node; lane owns 2 features (one
// dword of bf16x2). Bucket entries readfirstlane'd -> scalar s2 loads. ELU fused.
// ---------------------------------------------------------------------------
__device__ __forceinline__ float edge_w(float s1u, float s2d) {
  float sc = s1u + s2d;
  float lr = sc > 0.f ? sc : ALPHA * sc;
  return __expf(-lr);
}

__global__ __launch_bounds__(256) void agg_k(const int* __restrict__ cnt,
                                             const int* __restrict__ edst,
                                             const float* __restrict__ s1,
                                             const float* __restrict__ s2,
                                             const unsigned* __restrict__ hb,
                                             float* __restrict__ out) {
  int wid = blockIdx.x * 4 + (threadIdx.x >> 6);
  int lane = threadIdx.x & 63;
  if (wid >= N_NODES) return;
  int cn = __builtin_amdgcn_readfirstlane(cnt[wid]);
  if (cn > CAP) cn = CAP;
  float s1u = s1[wid];
  const int* bp = &edst[(size_t)wid * CAP];
  float accx = 0.f, accy = 0.f, rs = 0.f;
  int j = 0;
  for (; j + 3 < cn; j += 4) {
    int4 dd = *reinterpret_cast<const int4*>(&bp[j]);
    int d0 = __builtin_amdgcn_readfirstlane(dd.x);
    int d1 = __builtin_amdgcn_readfirstlane(dd.y);
    int d2 = __builtin_amdgcn_readfirstlane(dd.z);
    int d3 = __builtin_amdgcn_readfirstlane(dd.w);
    float w0 = edge_w(s1u, s2[d0]);
    float w1 = edge_w(s1u, s2[d1]);
    float w2 = edge_w(s1u, s2[d2]);
    float w3 = edge_w(s1u, s2[d3]);
    unsigned v0 = hb[(size_t)d0 * 64 + lane];
    unsigned v1 = hb[(size_t)d1 * 64 + lane];
    unsigned v2 = hb[(size_t)d2 * 64 + lane];
    unsigned v3 = hb[(size_t)d3 * 64 + lane];
    accx = fmaf(w0, __uint_as_float(v0 << 16), accx);
    accy = fmaf(w0, __uint_as_float(v0 & 0xFFFF0000u), accy);
    accx = fmaf(w1, __uint_as_float(v1 << 16), accx);
    accy = fmaf(w1, __uint_as_float(v1 & 0xFFFF0000u), accy);
    accx = fmaf(w2, __uint_as_float(v2 << 16), accx);
    accy = fmaf(w2, __uint_as_float(v2 & 0xFFFF0000u), accy);
    accx = fmaf(w3, __uint_as_float(v3 << 16), accx);
    accy = fmaf(w3, __uint_as_float(v3 & 0xFFFF0000u), accy);
    rs += (w0 + w1) + (w2 + w3);
  }
  for (; j < cn; ++j) {
    int d0 = __builtin_amdgcn_readfirstlane(bp[j]);
    float w0 = edge_w(s1u, s2[d0]);
    unsigned v0 = hb[(size_t)d0 * 64 + lane];
    accx = fmaf(w0, __uint_as_float(v0 << 16), accx);
    accy = fmaf(w0, __uint_as_float(v0 & 0xFFFF0000u), accy);
    rs += w0;
  }
  float inv = 1.0f / (rs + EPS);
  float px = accx * inv, py = accy * inv;
  px = px > 0.f ? px : expm1f(px);
  py = py > 0.f ? py : expm1f(py);
  float2 o = {px, py};
  *reinterpret_cast<float2*>(&out[(size_t)wid * OUT_F + lane * 2]) = o;
}

// ---------------------------------------------------------------------------
extern "C" void kernel_launch(void* const* d_in, const int* in_sizes, int n_in,
                              void* d_out, int out_size, void* d_ws, size_t ws_size,
                              hipStream_t stream) {
  const float* x = (const float*)d_in[0];
  const int* ei = (const int*)d_in[1];
  const float* W = (const float*)d_in[2];
  const float* a = (const float*)d_in[3];
  float* out = (float*)d_out;

  // workspace layout (4-byte units), total ~45.7 MB
  unsigned* hb = (unsigned*)d_ws;                   // 3,200,000 (bf16 h)
  float* s1 = (float*)(hb + (size_t)N_NODES * 64);  // 50,000
  float* s2 = s1 + N_NODES;                         // 50,000
  int* cnt = (int*)(s2 + N_NODES);                  // 50,000
  int* bincur = cnt + N_NODES;                      // 8   (zeroed with cnt)
  int* edst = bincur + RANGES;                      // 4,800,000 (50000*96)
  uint2* bins = (uint2*)(edst + (size_t)N_NODES * CAP); // 8*205000 uint2
  int* i64flag = (int*)(bins + (size_t)RANGES * BINCAP); // 1

  hipMemsetAsync(cnt, 0, ((size_t)N_NODES + RANGES) * sizeof(int), stream);

  detect_i64<<<1, 64, 0, stream>>>(ei, i64flag);
  gemm_xw<<<(N_NODES + G_ROWS - 1) / G_ROWS, 256, 0, stream>>>(x, W, a, hb, s1, s2);
  part_k<<<256, 256, 0, stream>>>(ei, i64flag, bins, bincur);
  fill2_k<<<256, 256, 0, stream>>>(bins, bincur, cnt, edst);
  agg_k<<<(N_NODES + 3) / 4, 256, 0, stream>>>(cnt, edst, s1, s2, hb, out);
}

// Round 7
// 216.925 us; speedup vs baseline: 1.0542x; 1.0542x over previous
//
#include <hip/hip_runtime.h>
#include <hip/hip_bf16.h>
#include <math.h>

#define N_NODES 50000
#define N_EDGES 1600000
#define IN_F 256
#define OUT_F 128
#define ALPHA 0.2f
#define EPS 1e-9f

#define RANGES 8                            // = #XCDs
#define NPR (N_NODES / RANGES)              // 6250 nodes per range
#define CAP 96                              // bucket capacity; P(deg>96)*N ~ 5e-14
#define TILE 2048                           // edges staged per part_k iteration
#define BINCAP 205000                       // per-range bin capacity (E=200000)

typedef __attribute__((ext_vector_type(8))) short short8v;  // 8 bf16 (4 VGPRs)
typedef __attribute__((ext_vector_type(4))) float f32x4;    // MFMA C/D frag

__device__ __forceinline__ unsigned short bf16r(float f) {  // RNE f32->bf16
  unsigned u = __float_as_uint(f);
  u = (u + 0x7FFFu + ((u >> 16) & 1u)) >> 16;
  return (unsigned short)u;
}

// ---------------------------------------------------------------------------
// Kernel 0: W (256x128 f32, row-major) -> Wt (128x256 bf16, col-major of W)
// ---------------------------------------------------------------------------
__global__ __launch_bounds__(256) void wcvt_k(const float* __restrict__ W,
                                              unsigned short* __restrict__ Wt) {
  int col = blockIdx.x;          // 0..127
  int k = threadIdx.x;           // 0..255
  Wt[col * IN_F + k] = bf16r(W[(size_t)k * OUT_F + col]);
}

// ---------------------------------------------------------------------------
// Kernel 1: h = x @ W via bf16 MFMA (16x16x32). Zero LDS.
// Block = 256 thr (4 waves) computes 128 rows x 128 cols; wave w owns cols
// [32w, 32w+32): B-slice register-resident. x converted f32->bf16 inline.
// Frag layouts (gfx950, verified C/D per guide):
//   A: row = lane&15,  k = 8*(lane>>4)+j
//   B: col = lane&15,  k = 8*(lane>>4)+j
//   D: col = lane&15,  row = 4*(lane>>4)+reg
// ---------------------------------------------------------------------------
__global__ __launch_bounds__(256) void gemm_mfma(const float* __restrict__ x,
                                                 const unsigned short* __restrict__ Wt,
                                                 unsigned short* __restrict__ hbs) {
  const int t = threadIdx.x;
  const int lane = t & 63;
  const int wv = t >> 6;                // 0..3
  const int row0 = blockIdx.x * 128;
  const int wcol0 = wv * 32;
  const int lrow = lane & 15;
  const int lk = (lane >> 4) * 8;

  // B frags: 2 colgrps x 8 ksteps, held in registers (64 VGPR)
  short8v b[2][8];
#pragma unroll
  for (int cg = 0; cg < 2; ++cg) {
    int col = wcol0 + cg * 16 + lrow;
#pragma unroll
    for (int ks = 0; ks < 8; ++ks)
      b[cg][ks] = *reinterpret_cast<const short8v*>(&Wt[col * IN_F + ks * 32 + lk]);
  }

  for (int rg = 0; rg < 8; ++rg) {
    int row = row0 + rg * 16 + lrow;
    int rowc = row < N_NODES ? row : N_NODES - 1;
    const float* xr = &x[(size_t)rowc * IN_F];
    short8v a[8];
#pragma unroll
    for (int ks = 0; ks < 8; ++ks) {
      float4 u = *reinterpret_cast<const float4*>(&xr[ks * 32 + lk]);
      float4 v = *reinterpret_cast<const float4*>(&xr[ks * 32 + lk + 4]);
      short8v av;
      av[0] = (short)bf16r(u.x); av[1] = (short)bf16r(u.y);
      av[2] = (short)bf16r(u.z); av[3] = (short)bf16r(u.w);
      av[4] = (short)bf16r(v.x); av[5] = (short)bf16r(v.y);
      av[6] = (short)bf16r(v.z); av[7] = (short)bf16r(v.w);
      a[ks] = av;
    }
    f32x4 acc0 = {0.f, 0.f, 0.f, 0.f};
    f32x4 acc1 = {0.f, 0.f, 0.f, 0.f};
#pragma unroll
    for (int ks = 0; ks < 8; ++ks) {
      acc0 = __builtin_amdgcn_mfma_f32_16x16x32_bf16(a[ks], b[0][ks], acc0, 0, 0, 0);
      acc1 = __builtin_amdgcn_mfma_f32_16x16x32_bf16(a[ks], b[1][ks], acc1, 0, 0, 0);
    }
    // store: lane holds D[4*(lane>>4)+r][lane&15] for each colgrp
    int srow0 = row0 + rg * 16 + (lane >> 4) * 4;
#pragma unroll
    for (int r = 0; r < 4; ++r) {
      int srow = srow0 + r;
      if (srow < N_NODES) {
        hbs[(size_t)srow * OUT_F + wcol0 + lrow] = bf16r(acc0[r]);
        hbs[(size_t)srow * OUT_F + wcol0 + 16 + lrow] = bf16r(acc1[r]);
      }
    }
  }
}

// ---------------------------------------------------------------------------
// Kernel 2: per-node scores from bf16 h: s1=h·a[0:128], s2=h·a[128:256]
// ---------------------------------------------------------------------------
__global__ __launch_bounds__(256) void scores_k(const unsigned* __restrict__ hb,
                                                const float* __restrict__ a,
                                                float* __restrict__ s1,
                                                float* __restrict__ s2) {
  int wid = blockIdx.x * 4 + (threadIdx.x >> 6);
  int lane = threadIdx.x & 63;
  if (wid >= N_NODES) return;
  unsigned v = hb[(size_t)wid * 64 + lane];        // cols 2*lane, 2*lane+1
  float h0 = __uint_as_float(v << 16);
  float h1 = __uint_as_float(v & 0xFFFF0000u);
  float p1 = h0 * a[2 * lane] + h1 * a[2 * lane + 1];
  float p2 = h0 * a[128 + 2 * lane] + h1 * a[129 + 2 * lane];
#pragma unroll
  for (int m = 32; m >= 1; m >>= 1) {
    p1 += __shfl_xor(p1, m, 64);
    p2 += __shfl_xor(p2, m, 64);
  }
  if (lane == 0) { s1[wid] = p1; s2[wid] = p2; }
}

// ---------------------------------------------------------------------------
// int32-vs-int64 detection (values < 50000 => odd words all zero)
// ---------------------------------------------------------------------------
__global__ void detect_i64(const int* __restrict__ ei, int* __restrict__ flag) {
  int lane = threadIdx.x & 63;
  int nz = 0;
#pragma unroll
  for (int j = 0; j < 4; ++j)
    nz |= ei[2 * (lane + j * 64) + 1];
  unsigned long long anynz = __ballot(nz != 0);
  if (lane == 0) *flag = (anynz == 0ull) ? 1 : 0;
}

__device__ __forceinline__ int load_idx(const int* __restrict__ ei32, int isI64,
                                        long long pos) {
  if (isI64) return (int)(reinterpret_cast<const long long*>(ei32)[pos]);
  return ei32[pos];
}

// ---------------------------------------------------------------------------
// Kernel 3: radix partition of edges into 8 node-range bins (LDS counting
// sort per 2048-edge tile; contiguous segment writes -> full-line writebacks)
// ---------------------------------------------------------------------------
__global__ __launch_bounds__(256) void part_k(const int* __restrict__ ei,
                                              const int* __restrict__ i64flag,
                                              uint2* __restrict__ bins,
                                              int* __restrict__ bincur) {
  __shared__ uint2 buf[TILE];            // 16 KB
  __shared__ int hist[RANGES], pre[RANGES + 1], cur[RANGES], gbase[RANGES];
  const int t = threadIdx.x;
  const int f64 = *i64flag;
  const int ntiles = (N_EDGES + TILE - 1) / TILE;
  for (int tile = blockIdx.x; tile < ntiles; tile += gridDim.x) {
    const int base = tile * TILE;
    if (t < RANGES) hist[t] = 0;
    __syncthreads();
    int ss[8], dd[8], bb[8];
#pragma unroll
    for (int j = 0; j < 8; ++j) {
      int e = base + j * 256 + t;
      if (e < N_EDGES) {
        ss[j] = load_idx(ei, f64, e);
        dd[j] = load_idx(ei, f64, (long long)N_EDGES + e);
        bb[j] = (int)((unsigned)ss[j] / (unsigned)NPR);
        atomicAdd(&hist[bb[j]], 1);
      } else {
        bb[j] = -1; ss[j] = 0; dd[j] = 0;
      }
    }
    __syncthreads();
    if (t == 0) {
      int run = 0;
#pragma unroll
      for (int b = 0; b < RANGES; ++b) { pre[b] = run; run += hist[b]; }
      pre[RANGES] = run;
    }
    if (t < RANGES) gbase[t] = atomicAdd(&bincur[t], hist[t]);
    __syncthreads();
    if (t < RANGES) cur[t] = pre[t];
    __syncthreads();
#pragma unroll
    for (int j = 0; j < 8; ++j) {
      if (bb[j] >= 0) {
        int pos = atomicAdd(&cur[bb[j]], 1);
        buf[pos] = make_uint2((unsigned)ss[j], (unsigned)dd[j]);
      }
    }
    __syncthreads();
    const int tot = pre[RANGES];
    for (int i = t; i < tot; i += 256) {
      uint2 v = buf[i];
      int b = (int)(v.x / (unsigned)NPR);
      long long o = (long long)gbase[b] + (i - pre[b]);
      if (o < BINCAP) bins[(size_t)b * BINCAP + o] = v;
    }
    __syncthreads();
  }
}

// ---------------------------------------------------------------------------
// Kernel 4: bucket fill from XCD-local bin (working set ~4 MB per XCD L2)
// ---------------------------------------------------------------------------
__global__ __launch_bounds__(256) void fill2_k(const uint2* __restrict__ bins,
                                               const int* __restrict__ bincur,
                                               int* __restrict__ cnt,
                                               int* __restrict__ edst) {
  const int r = blockIdx.x & 7;
  const int sub = blockIdx.x >> 3;
  const int nsub = gridDim.x >> 3;
  int n_r = bincur[r];
  if (n_r > BINCAP) n_r = BINCAP;
  const uint2* bp = bins + (size_t)r * BINCAP;
  for (int i = sub * 256 + threadIdx.x; i < n_r; i += nsub * 256) {
    uint2 v = bp[i];
    int p = atomicAdd(&cnt[v.x], 1);
    if (p < CAP) edst[(size_t)v.x * CAP + p] = (int)v.y;
  }
}

// ---------------------------------------------------------------------------
// Kernel 5: gather-aggregate. One wave per node; lane owns 2 features.
// ---------------------------------------------------------------------------
__device__ __forceinline__ float edge_w(float s1u, float s2d) {
  float sc = s1u + s2d;
  float lr = sc > 0.f ? sc : ALPHA * sc;
  return __expf(-lr);
}

__global__ __launch_bounds__(256) void agg_k(const int* __restrict__ cnt,
                                             const int* __restrict__ edst,
                                             const float* __restrict__ s1,
                                             const float* __restrict__ s2,
                                             const unsigned* __restrict__ hb,
                                             float* __restrict__ out) {
  int wid = blockIdx.x * 4 + (threadIdx.x >> 6);
  int lane = threadIdx.x & 63;
  if (wid >= N_NODES) return;
  int cn = __builtin_amdgcn_readfirstlane(cnt[wid]);
  if (cn > CAP) cn = CAP;
  float s1u = s1[wid];
  const int* bp = &edst[(size_t)wid * CAP];
  float accx = 0.f, accy = 0.f, rs = 0.f;
  int j = 0;
  for (; j + 3 < cn; j += 4) {
    int4 dd = *reinterpret_cast<const int4*>(&bp[j]);
    int d0 = __builtin_amdgcn_readfirstlane(dd.x);
    int d1 = __builtin_amdgcn_readfirstlane(dd.y);
    int d2 = __builtin_amdgcn_readfirstlane(dd.z);
    int d3 = __builtin_amdgcn_readfirstlane(dd.w);
    float w0 = edge_w(s1u, s2[d0]);
    float w1 = edge_w(s1u, s2[d1]);
    float w2 = edge_w(s1u, s2[d2]);
    float w3 = edge_w(s1u, s2[d3]);
    unsigned v0 = hb[(size_t)d0 * 64 + lane];
    unsigned v1 = hb[(size_t)d1 * 64 + lane];
    unsigned v2 = hb[(size_t)d2 * 64 + lane];
    unsigned v3 = hb[(size_t)d3 * 64 + lane];
    accx = fmaf(w0, __uint_as_float(v0 << 16), accx);
    accy = fmaf(w0, __uint_as_float(v0 & 0xFFFF0000u), accy);
    accx = fmaf(w1, __uint_as_float(v1 << 16), accx);
    accy = fmaf(w1, __uint_as_float(v1 & 0xFFFF0000u), accy);
    accx = fmaf(w2, __uint_as_float(v2 << 16), accx);
    accy = fmaf(w2, __uint_as_float(v2 & 0xFFFF0000u), accy);
    accx = fmaf(w3, __uint_as_float(v3 << 16), accx);
    accy = fmaf(w3, __uint_as_float(v3 & 0xFFFF0000u), accy);
    rs += (w0 + w1) + (w2 + w3);
  }
  for (; j < cn; ++j) {
    int d0 = __builtin_amdgcn_readfirstlane(bp[j]);
    float w0 = edge_w(s1u, s2[d0]);
    unsigned v0 = hb[(size_t)d0 * 64 + lane];
    accx = fmaf(w0, __uint_as_float(v0 << 16), accx);
    accy = fmaf(w0, __uint_as_float(v0 & 0xFFFF0000u), accy);
    rs += w0;
  }
  float inv = 1.0f / (rs + EPS);
  float px = accx * inv, py = accy * inv;
  px = px > 0.f ? px : expm1f(px);
  py = py > 0.f ? py : expm1f(py);
  float2 o = {px, py};
  *reinterpret_cast<float2*>(&out[(size_t)wid * OUT_F + lane * 2]) = o;
}

// ---------------------------------------------------------------------------
extern "C" void kernel_launch(void* const* d_in, const int* in_sizes, int n_in,
                              void* d_out, int out_size, void* d_ws, size_t ws_size,
                              hipStream_t stream) {
  const float* x = (const float*)d_in[0];
  const int* ei = (const int*)d_in[1];
  const float* W = (const float*)d_in[2];
  const float* a = (const float*)d_in[3];
  float* out = (float*)d_out;

  // workspace layout (4-byte units), total ~45.8 MB
  unsigned* hb = (unsigned*)d_ws;                        // 3,200,000 (bf16 h)
  float* s1 = (float*)(hb + (size_t)N_NODES * 64);       // 50,000
  float* s2 = s1 + N_NODES;                              // 50,000
  int* cnt = (int*)(s2 + N_NODES);                       // 50,000
  int* bincur = cnt + N_NODES;                           // 8 (zeroed with cnt)
  int* edst = bincur + RANGES;                           // 4,800,000
  uint2* bins = (uint2*)(edst + (size_t)N_NODES * CAP);  // 8*205000 uint2
  int* i64flag = (int*)(bins + (size_t)RANGES * BINCAP); // 1
  unsigned short* Wt = (unsigned short*)(i64flag + 1);   // 32768 bf16

  hipMemsetAsync(cnt, 0, ((size_t)N_NODES + RANGES) * sizeof(int), stream);

  detect_i64<<<1, 64, 0, stream>>>(ei, i64flag);
  wcvt_k<<<OUT_F, IN_F, 0, stream>>>(W, Wt);
  gemm_mfma<<<(N_NODES + 127) / 128, 256, 0, stream>>>(x, Wt, (unsigned short*)hb);
  scores_k<<<(N_NODES + 3) / 4, 256, 0, stream>>>(hb, a, s1, s2);
  part_k<<<256, 256, 0, stream>>>(ei, i64flag, bins, bincur);
  fill2_k<<<256, 256, 0, stream>>>(bins, bincur, cnt, edst);
  agg_k<<<(N_NODES + 3) / 4, 256, 0, stream>>>(cnt, edst, s1, s2, hb, out);
}

// Round 8
// 209.040 us; speedup vs baseline: 1.0940x; 1.0377x over previous
//
#include <hip/hip_runtime.h>
#include <hip/hip_bf16.h>
#include <math.h>

#define N_NODES 50000
#define N_EDGES 1600000
#define IN_F 256
#define OUT_F 128
#define ALPHA 0.2f
#define EPS 1e-9f

#define RANGES 8                            // = #XCDs
#define NPR (N_NODES / RANGES)              // 6250 nodes per range
#define CAP 96                              // bucket capacity; P(deg>96)*N ~ 5e-14
#define TILE 2048                           // edges staged per part_k iteration
#define BINCAP 205000                       // per-range bin capacity (E=200000)

typedef __attribute__((ext_vector_type(8))) short short8v;  // 8 bf16 (4 VGPRs)
typedef __attribute__((ext_vector_type(4))) float f32x4;    // MFMA C/D frag

__device__ __forceinline__ unsigned short bf16r(float f) {  // RNE f32->bf16
  unsigned u = __float_as_uint(f);
  u = (u + 0x7FFFu + ((u >> 16) & 1u)) >> 16;
  return (unsigned short)u;
}

// ---------------------------------------------------------------------------
// Kernel 0: W (256x128 f32, row-major) -> Wt (128x256 bf16, col-major of W)
// ---------------------------------------------------------------------------
__global__ __launch_bounds__(256) void wcvt_k(const float* __restrict__ W,
                                              unsigned short* __restrict__ Wt) {
  int col = blockIdx.x;          // 0..127
  int k = threadIdx.x;           // 0..255
  Wt[col * IN_F + k] = bf16r(W[(size_t)k * OUT_F + col]);
}

// ---------------------------------------------------------------------------
// Kernel 1: h = x @ W via bf16 MFMA (16x16x32). Zero LDS. Block = 4 waves,
// 128 rows x 128 cols; wave owns 32 cols, B register-resident.
// ---------------------------------------------------------------------------
__global__ __launch_bounds__(256) void gemm_mfma(const float* __restrict__ x,
                                                 const unsigned short* __restrict__ Wt,
                                                 unsigned short* __restrict__ hbs) {
  const int t = threadIdx.x;
  const int lane = t & 63;
  const int wv = t >> 6;                // 0..3
  const int row0 = blockIdx.x * 128;
  const int wcol0 = wv * 32;
  const int lrow = lane & 15;
  const int lk = (lane >> 4) * 8;

  short8v b[2][8];
#pragma unroll
  for (int cg = 0; cg < 2; ++cg) {
    int col = wcol0 + cg * 16 + lrow;
#pragma unroll
    for (int ks = 0; ks < 8; ++ks)
      b[cg][ks] = *reinterpret_cast<const short8v*>(&Wt[col * IN_F + ks * 32 + lk]);
  }

  for (int rg = 0; rg < 8; ++rg) {
    int row = row0 + rg * 16 + lrow;
    int rowc = row < N_NODES ? row : N_NODES - 1;
    const float* xr = &x[(size_t)rowc * IN_F];
    short8v a[8];
#pragma unroll
    for (int ks = 0; ks < 8; ++ks) {
      float4 u = *reinterpret_cast<const float4*>(&xr[ks * 32 + lk]);
      float4 v = *reinterpret_cast<const float4*>(&xr[ks * 32 + lk + 4]);
      short8v av;
      av[0] = (short)bf16r(u.x); av[1] = (short)bf16r(u.y);
      av[2] = (short)bf16r(u.z); av[3] = (short)bf16r(u.w);
      av[4] = (short)bf16r(v.x); av[5] = (short)bf16r(v.y);
      av[6] = (short)bf16r(v.z); av[7] = (short)bf16r(v.w);
      a[ks] = av;
    }
    f32x4 acc0 = {0.f, 0.f, 0.f, 0.f};
    f32x4 acc1 = {0.f, 0.f, 0.f, 0.f};
#pragma unroll
    for (int ks = 0; ks < 8; ++ks) {
      acc0 = __builtin_amdgcn_mfma_f32_16x16x32_bf16(a[ks], b[0][ks], acc0, 0, 0, 0);
      acc1 = __builtin_amdgcn_mfma_f32_16x16x32_bf16(a[ks], b[1][ks], acc1, 0, 0, 0);
    }
    int srow0 = row0 + rg * 16 + (lane >> 4) * 4;
#pragma unroll
    for (int r = 0; r < 4; ++r) {
      int srow = srow0 + r;
      if (srow < N_NODES) {
        hbs[(size_t)srow * OUT_F + wcol0 + lrow] = bf16r(acc0[r]);
        hbs[(size_t)srow * OUT_F + wcol0 + 16 + lrow] = bf16r(acc1[r]);
      }
    }
  }
}

// ---------------------------------------------------------------------------
// Kernel 2: per-node scores from bf16 h: s1=h·a[0:128], s2=h·a[128:256]
// ---------------------------------------------------------------------------
__global__ __launch_bounds__(256) void scores_k(const unsigned* __restrict__ hb,
                                                const float* __restrict__ a,
                                                float* __restrict__ s1,
                                                float* __restrict__ s2) {
  int wid = blockIdx.x * 4 + (threadIdx.x >> 6);
  int lane = threadIdx.x & 63;
  if (wid >= N_NODES) return;
  unsigned v = hb[(size_t)wid * 64 + lane];        // cols 2*lane, 2*lane+1
  float h0 = __uint_as_float(v << 16);
  float h1 = __uint_as_float(v & 0xFFFF0000u);
  float p1 = h0 * a[2 * lane] + h1 * a[2 * lane + 1];
  float p2 = h0 * a[128 + 2 * lane] + h1 * a[129 + 2 * lane];
#pragma unroll
  for (int m = 32; m >= 1; m >>= 1) {
    p1 += __shfl_xor(p1, m, 64);
    p2 += __shfl_xor(p2, m, 64);
  }
  if (lane == 0) { s1[wid] = p1; s2[wid] = p2; }
}

__device__ __forceinline__ int load_idx(const int* __restrict__ ei32, int isI64,
                                        long long pos) {
  if (isI64) return (int)(reinterpret_cast<const long long*>(ei32)[pos]);
  return ei32[pos];
}

// ---------------------------------------------------------------------------
// Kernel 3: radix partition of edges into 8 node-range bins (LDS counting
// sort per 2048-edge tile; contiguous segment writes). int64-vs-int32 input
// layout detected per-block (values<50000 => odd words all zero).
// ---------------------------------------------------------------------------
__global__ __launch_bounds__(256) void part_k(const int* __restrict__ ei,
                                              uint2* __restrict__ bins,
                                              int* __restrict__ bincur) {
  __shared__ uint2 buf[TILE];            // 16 KB
  __shared__ int hist[RANGES], pre[RANGES + 1], cur[RANGES], gbase[RANGES];
  __shared__ int sf64;
  const int t = threadIdx.x;
  if (t < 64) {                           // wave 0: detect int64 layout
    int nz = 0;
#pragma unroll
    for (int j = 0; j < 4; ++j)
      nz |= ei[2 * (t + j * 64) + 1];
    unsigned long long anynz = __ballot(nz != 0);
    if (t == 0) sf64 = (anynz == 0ull) ? 1 : 0;
  }
  __syncthreads();
  const int f64 = sf64;
  const int ntiles = (N_EDGES + TILE - 1) / TILE;
  for (int tile = blockIdx.x; tile < ntiles; tile += gridDim.x) {
    const int base = tile * TILE;
    if (t < RANGES) hist[t] = 0;
    __syncthreads();
    int ss[8], dd[8], bb[8];
#pragma unroll
    for (int j = 0; j < 8; ++j) {
      int e = base + j * 256 + t;
      if (e < N_EDGES) {
        ss[j] = load_idx(ei, f64, e);
        dd[j] = load_idx(ei, f64, (long long)N_EDGES + e);
        bb[j] = (int)((unsigned)ss[j] / (unsigned)NPR);
        atomicAdd(&hist[bb[j]], 1);
      } else {
        bb[j] = -1; ss[j] = 0; dd[j] = 0;
      }
    }
    __syncthreads();
    if (t == 0) {
      int run = 0;
#pragma unroll
      for (int b = 0; b < RANGES; ++b) { pre[b] = run; run += hist[b]; }
      pre[RANGES] = run;
    }
    if (t < RANGES) gbase[t] = atomicAdd(&bincur[t], hist[t]);
    __syncthreads();
    if (t < RANGES) cur[t] = pre[t];
    __syncthreads();
#pragma unroll
    for (int j = 0; j < 8; ++j) {
      if (bb[j] >= 0) {
        int pos = atomicAdd(&cur[bb[j]], 1);
        buf[pos] = make_uint2((unsigned)ss[j], (unsigned)dd[j]);
      }
    }
    __syncthreads();
    const int tot = pre[RANGES];
    for (int i = t; i < tot; i += 256) {
      uint2 v = buf[i];
      int b = (int)(v.x / (unsigned)NPR);
      long long o = (long long)gbase[b] + (i - pre[b]);
      if (o < BINCAP) bins[(size_t)b * BINCAP + o] = v;
    }
    __syncthreads();
  }
}

// ---------------------------------------------------------------------------
// Kernel 4: bucket fill from XCD-local bin. Grid 2048 (8 blocks/CU) for
// latency hiding; bid&7 keeps range->XCD affinity.
// ---------------------------------------------------------------------------
__global__ __launch_bounds__(256) void fill2_k(const uint2* __restrict__ bins,
                                               const int* __restrict__ bincur,
                                               int* __restrict__ cnt,
                                               int* __restrict__ edst) {
  const int r = blockIdx.x & 7;
  const int sub = blockIdx.x >> 3;
  const int nsub = gridDim.x >> 3;
  int n_r = bincur[r];
  if (n_r > BINCAP) n_r = BINCAP;
  const uint2* bp = bins + (size_t)r * BINCAP;
  for (int i = sub * 256 + threadIdx.x; i < n_r; i += nsub * 256) {
    uint2 v = bp[i];
    int p = atomicAdd(&cnt[v.x], 1);
    if (p < CAP) edst[(size_t)v.x * CAP + p] = (int)v.y;
  }
}

// ---------------------------------------------------------------------------
// Kernel 5: gather-aggregate. One wave per node; lane owns 2 features.
// Pre-pass: lane j computes w for edge j (<=2 passes) into LDS; main loop
// reads w as wave-uniform float4 broadcast -> removes redundant 64-lane
// edge_w recompute (was ~60% of VALU).
// ---------------------------------------------------------------------------
__device__ __forceinline__ float edge_w(float s1u, float s2d) {
  float sc = s1u + s2d;
  float lr = fmaxf(sc, ALPHA * sc);   // leaky_relu == max(sc, 0.2*sc)
  return __expf(-lr);
}

__global__ __launch_bounds__(256) void agg_k(const int* __restrict__ cnt,
                                             const int* __restrict__ edst,
                                             const float* __restrict__ s1,
                                             const float* __restrict__ s2,
                                             const unsigned* __restrict__ hb,
                                             float* __restrict__ out) {
  __shared__ float wbuf[4][CAP];       // 1.5 KB
  int wslot = threadIdx.x >> 6;
  int wid = blockIdx.x * 4 + wslot;
  int lane = threadIdx.x & 63;
  if (wid >= N_NODES) return;
  int cn = __builtin_amdgcn_readfirstlane(cnt[wid]);
  if (cn > CAP) cn = CAP;
  float s1u = s1[wid];
  const int* bp = &edst[(size_t)wid * CAP];
  // pre-pass: per-lane w computation (edges lane, lane+64)
  for (int j = lane; j < cn; j += 64)
    wbuf[wslot][j] = edge_w(s1u, s2[bp[j]]);
  // same-wave DS producer/consumer: no barrier needed
  float accx = 0.f, accy = 0.f, rs = 0.f;
  int j = 0;
  for (; j + 3 < cn; j += 4) {
    int4 dd = *reinterpret_cast<const int4*>(&bp[j]);
    int d0 = __builtin_amdgcn_readfirstlane(dd.x);
    int d1 = __builtin_amdgcn_readfirstlane(dd.y);
    int d2 = __builtin_amdgcn_readfirstlane(dd.z);
    int d3 = __builtin_amdgcn_readfirstlane(dd.w);
    float4 wv = *reinterpret_cast<const float4*>(&wbuf[wslot][j]);  // broadcast
    unsigned v0 = hb[(size_t)d0 * 64 + lane];
    unsigned v1 = hb[(size_t)d1 * 64 + lane];
    unsigned v2 = hb[(size_t)d2 * 64 + lane];
    unsigned v3 = hb[(size_t)d3 * 64 + lane];
    accx = fmaf(wv.x, __uint_as_float(v0 << 16), accx);
    accy = fmaf(wv.x, __uint_as_float(v0 & 0xFFFF0000u), accy);
    accx = fmaf(wv.y, __uint_as_float(v1 << 16), accx);
    accy = fmaf(wv.y, __uint_as_float(v1 & 0xFFFF0000u), accy);
    accx = fmaf(wv.z, __uint_as_float(v2 << 16), accx);
    accy = fmaf(wv.z, __uint_as_float(v2 & 0xFFFF0000u), accy);
    accx = fmaf(wv.w, __uint_as_float(v3 << 16), accx);
    accy = fmaf(wv.w, __uint_as_float(v3 & 0xFFFF0000u), accy);
    rs += (wv.x + wv.y) + (wv.z + wv.w);
  }
  for (; j < cn; ++j) {
    int d0 = __builtin_amdgcn_readfirstlane(bp[j]);
    float w0 = wbuf[wslot][j];
    unsigned v0 = hb[(size_t)d0 * 64 + lane];
    accx = fmaf(w0, __uint_as_float(v0 << 16), accx);
    accy = fmaf(w0, __uint_as_float(v0 & 0xFFFF0000u), accy);
    rs += w0;
  }
  float inv = 1.0f / (rs + EPS);
  float px = accx * inv, py = accy * inv;
  px = px > 0.f ? px : expm1f(px);
  py = py > 0.f ? py : expm1f(py);
  float2 o = {px, py};
  *reinterpret_cast<float2*>(&out[(size_t)wid * OUT_F + lane * 2]) = o;
}

// ---------------------------------------------------------------------------
extern "C" void kernel_launch(void* const* d_in, const int* in_sizes, int n_in,
                              void* d_out, int out_size, void* d_ws, size_t ws_size,
                              hipStream_t stream) {
  const float* x = (const float*)d_in[0];
  const int* ei = (const int*)d_in[1];
  const float* W = (const float*)d_in[2];
  const float* a = (const float*)d_in[3];
  float* out = (float*)d_out;

  // workspace layout (4-byte units), total ~45.8 MB
  unsigned* hb = (unsigned*)d_ws;                        // 3,200,000 (bf16 h)
  float* s1 = (float*)(hb + (size_t)N_NODES * 64);       // 50,000
  float* s2 = s1 + N_NODES;                              // 50,000
  int* cnt = (int*)(s2 + N_NODES);                       // 50,000
  int* bincur = cnt + N_NODES;                           // 8 (zeroed with cnt)
  int* edst = bincur + RANGES;                           // 4,800,000
  uint2* bins = (uint2*)(edst + (size_t)N_NODES * CAP);  // 8*205000 uint2
  unsigned short* Wt = (unsigned short*)(bins + (size_t)RANGES * BINCAP); // 32768 bf16

  hipMemsetAsync(cnt, 0, ((size_t)N_NODES + RANGES) * sizeof(int), stream);

  wcvt_k<<<OUT_F, IN_F, 0, stream>>>(W, Wt);
  gemm_mfma<<<(N_NODES + 127) / 128, 256, 0, stream>>>(x, Wt, (unsigned short*)hb);
  scores_k<<<(N_NODES + 3) / 4, 256, 0, stream>>>(hb, a, s1, s2);
  part_k<<<391, 256, 0, stream>>>(ei, bins, bincur);
  fill2_k<<<2048, 256, 0, stream>>>(bins, bincur, cnt, edst);
  agg_k<<<(N_NODES + 3) / 4, 256, 0, stream>>>(cnt, edst, s1, s2, hb, out);
}